// Round 5
// baseline (1063.884 us; speedup 1.0000x reference)
//
#include <hip/hip_runtime.h>
#include <hip/hip_bf16.h>

typedef unsigned short ushort_t;
typedef short short8 __attribute__((ext_vector_type(8)));
typedef unsigned short ushort8 __attribute__((ext_vector_type(8)));
typedef unsigned short ushortx4 __attribute__((ext_vector_type(4)));
typedef float fx4 __attribute__((ext_vector_type(4)));
typedef int ix4 __attribute__((ext_vector_type(4)));

#define MFMA(a, b, c) __builtin_amdgcn_mfma_f32_16x16x32_bf16((a), (b), (c), 0, 0, 0)

__device__ __forceinline__ ushort_t f2bf(float f) {
  __hip_bfloat16 h = __float2bfloat16(f);
  return *(ushort_t*)&h;
}
__device__ __forceinline__ float bf2f(ushort_t h) {
  union { unsigned u; float f; } c; c.u = ((unsigned)h) << 16;
  return c.f;
}
__device__ __forceinline__ void gload16(const ushort_t* g, ushort_t* l) {
  __builtin_amdgcn_global_load_lds((const __attribute__((address_space(1))) void*)g,
                                   (__attribute__((address_space(3))) void*)l, 16, 0, 0);
}

// ---------------- f32 -> bf16 convert for the 4 weight matrices ----------------
__global__ __launch_bounds__(256) void cvt4_kernel(const float* __restrict__ s0,
                                                   const float* __restrict__ s1,
                                                   const float* __restrict__ s2,
                                                   const float* __restrict__ s3,
                                                   ushort_t* __restrict__ d0,
                                                   ushort_t* __restrict__ d1,
                                                   ushort_t* __restrict__ d2,
                                                   ushort_t* __restrict__ d3) {
  int bi = blockIdx.x;
  const float* src = (bi < 1024) ? s0 : (bi < 2048) ? s1 : (bi < 3072) ? s2 : s3;
  ushort_t* dst = (bi < 1024) ? d0 : (bi < 2048) ? d1 : (bi < 3072) ? d2 : d3;
  int i = (bi & 1023) * 256 + threadIdx.x;
  fx4 v = *(const fx4*)&src[(size_t)i * 4];
  ushortx4 o;
#pragma unroll
  for (int j = 0; j < 4; ++j) o[j] = f2bf(v[j]);
  *(ushortx4*)&dst[(size_t)i * 4] = o;
}

// ---------------- LayerNorm: x (f32, row=1024) -> xn (bf16) ----------------
__global__ __launch_bounds__(256) void ln_kernel(const float* __restrict__ x,
                                                 const float* __restrict__ sc,
                                                 const float* __restrict__ bi,
                                                 ushort_t* __restrict__ xn) {
  __shared__ float red[8];
  int row = blockIdx.x, tid = threadIdx.x;
  const float* xr = x + (size_t)row * 1024;
  fx4 v = *(const fx4*)&xr[tid * 4];
  float s = v[0] + v[1] + v[2] + v[3];
  float s2 = v[0] * v[0] + v[1] * v[1] + v[2] * v[2] + v[3] * v[3];
#pragma unroll
  for (int m = 32; m >= 1; m >>= 1) {
    s += __shfl_xor(s, m);
    s2 += __shfl_xor(s2, m);
  }
  int wave = tid >> 6;
  if ((tid & 63) == 0) { red[wave * 2] = s; red[wave * 2 + 1] = s2; }
  __syncthreads();
  s = red[0] + red[2] + red[4] + red[6];
  s2 = red[1] + red[3] + red[5] + red[7];
  float mu = s * (1.f / 1024.f);
  float var = s2 * (1.f / 1024.f) - mu * mu;
  float rs = rsqrtf(var + 1e-5f);
  fx4 scv = *(const fx4*)&sc[tid * 4];
  fx4 biv = *(const fx4*)&bi[tid * 4];
  ushortx4 o;
#pragma unroll
  for (int j = 0; j < 4; ++j) o[j] = f2bf((v[j] - mu) * rs * scv[j] + biv[j]);
  *(ushortx4*)&xn[(size_t)row * 1024 + tid * 4] = o;
}

// ---------------- mask (int32) -> 1 bit per (b,t,s) ----------------
__global__ __launch_bounds__(256) void maskpack_kernel(const int* __restrict__ mask,
                                                       unsigned* __restrict__ bits) {
  __shared__ unsigned char nib[256];
  int row = blockIdx.x, tid = threadIdx.x;
  ix4 m = *(const ix4*)&mask[(size_t)row * 1024 + tid * 4];
  nib[tid] = (unsigned char)((m[0] != 0 ? 1 : 0) | (m[1] != 0 ? 2 : 0) |
                             (m[2] != 0 ? 4 : 0) | (m[3] != 0 ? 8 : 0));
  __syncthreads();
  if (tid < 32) {
    unsigned w = 0;
#pragma unroll
    for (int j = 0; j < 8; ++j) w |= ((unsigned)nib[tid * 8 + j]) << (j * 4);
    bits[(size_t)row * 32 + tid] = w;
  }
}

// ---------------- GEMM: C[M][N] = A[M][K] @ B[N][K]^T + bias ----------------
template <int F32OUT>
__global__ __launch_bounds__(256) void gemm_bt(const ushort_t* __restrict__ A,
                                               const ushort_t* __restrict__ B,
                                               const float* __restrict__ bias, void* C,
                                               int M, int N, int K) {
  __shared__ ushort_t lA[4096];  // [128][32] linear
  __shared__ ushort_t lB[4096];
  int bm = blockIdx.y * 128, bn = blockIdx.x * 128;
  int tid = threadIdx.x;
  int wave = tid >> 6, lane = tid & 63;
  int wm = (wave >> 1) * 64, wn = (wave & 1) * 64;
  int l15 = lane & 15, lg = lane >> 4;
  int r0 = tid >> 2, c0 = (tid & 3) * 8;
  int g1 = 256 + tid, r1 = g1 >> 2, c1 = (g1 & 3) * 8;
  int lb0 = (wave * 64) * 8;
  int lb1 = (256 + wave * 64) * 8;
  fx4 acc[4][4] = {};
  for (int k0 = 0; k0 < K; k0 += 32) {
    __syncthreads();
    gload16(&A[(size_t)(bm + r0) * K + k0 + c0], &lA[lb0]);
    gload16(&A[(size_t)(bm + r1) * K + k0 + c1], &lA[lb1]);
    gload16(&B[(size_t)(bn + r0) * K + k0 + c0], &lB[lb0]);
    gload16(&B[(size_t)(bn + r1) * K + k0 + c1], &lB[lb1]);
    __syncthreads();
    short8 af[4], bf[4];
#pragma unroll
    for (int i = 0; i < 4; ++i) af[i] = *(const short8*)&lA[(wm + i * 16 + l15) * 32 + lg * 8];
#pragma unroll
    for (int i = 0; i < 4; ++i) bf[i] = *(const short8*)&lB[(wn + i * 16 + l15) * 32 + lg * 8];
#pragma unroll
    for (int i = 0; i < 4; ++i)
#pragma unroll
      for (int j = 0; j < 4; ++j) acc[i][j] = MFMA(af[i], bf[j], acc[i][j]);
  }
#pragma unroll
  for (int j = 0; j < 4; ++j) {
    int n = bn + wn + j * 16 + l15;
    float bv = bias[n];
#pragma unroll
    for (int i = 0; i < 4; ++i) {
      int mr = bm + wm + i * 16 + lg * 4;
#pragma unroll
      for (int r = 0; r < 4; ++r) {
        float val = acc[i][j][r] + bv;
        if (F32OUT)
          ((float*)C)[(size_t)(mr + r) * N + n] = val;
        else
          ((ushort_t*)C)[(size_t)(mr + r) * N + n] = f2bf(val);
      }
    }
  }
}

// ---------------- B_all[bh][t][s] = sum_d q[b,t,h*64+d] * pos_k[t,s,d] ----------------
// v4: launch_bounds(256,4) so the 2-deep pos_k register pipeline fits (r4: compiler
// sank prefetch at 52 VGPR); COMPUTE split into two 4-row halves (acc 16 regs).
__global__ __launch_bounds__(256, 4) void ball_kernel(const ushort_t* __restrict__ q,
                                                      const float* __restrict__ pos_k,
                                                      ushort_t* __restrict__ B_all) {
  __shared__ ushort_t lq[128 * 64];  // rows of 128 B, col-byte ^= (row&7)<<4
  int t = blockIdx.y, sx = blockIdx.x;
  int tid = threadIdx.x, wave = tid >> 6, lane = tid & 63, l15 = lane & 15, lg = lane >> 4;

  const float* pk = pos_k + (size_t)t * 65536;
  int sw = sx * 512 + wave * 128;
  const float* base = pk + (size_t)(sw + l15) * 64 + lg * 8;

  fx4 a0, a1, a2, a3, b0, b1, b2, b3;
#define LOADSET(v0, v1, v2, v3, c)                \
  {                                               \
    const float* p_ = base + (size_t)(c) * 1024;  \
    v0 = *(const fx4*)p_;                         \
    v1 = *(const fx4*)(p_ + 4);                   \
    v2 = *(const fx4*)(p_ + 32);                  \
    v3 = *(const fx4*)(p_ + 36);                  \
  }
  LOADSET(a0, a1, a2, a3, 0)
  LOADSET(b0, b1, b2, b3, 1)

  // stage q[t]: 128 bh-rows x 64 bf16 (16 KB), swizzled
#pragma unroll
  for (int it = 0; it < 4; ++it) {
    int u = tid + it * 256;           // 0..1023 16B-units
    int row = u >> 3, cu = u & 7;     // row=bh, cu=16B col unit
    ushort8 vv = *(const ushort8*)&q[((size_t)((row >> 4) * 1024 + t)) * 1024 + (row & 15) * 64 + cu * 8];
    *(ushort8*)&lq[(row * 128 + ((cu * 16) ^ ((row & 7) << 4))) >> 1] = vv;
  }
  __syncthreads();

#define CVT(af0, af1, v0, v1, v2, v3)                              \
  {                                                                \
    _Pragma("unroll") for (int j_ = 0; j_ < 4; ++j_) {             \
      af0[j_] = (short)f2bf(v0[j_]); af0[j_ + 4] = (short)f2bf(v1[j_]); \
      af1[j_] = (short)f2bf(v2[j_]); af1[j_ + 4] = (short)f2bf(v3[j_]); \
    }                                                              \
  }

#define COMPUTE(af0, af1, c)                                                          \
  {                                                                                   \
    int sb_ = sw + (c) * 16;                                                          \
    fx4 z_ = {};                                                                      \
    _Pragma("unroll") for (int jh_ = 0; jh_ < 2; ++jh_) {                             \
      fx4 acc_[4];                                                                    \
      _Pragma("unroll") for (int j_ = 0; j_ < 4; ++j_) {                              \
        int row_ = (jh_ * 4 + j_) * 16 + l15;                                         \
        int cb_ = (row_ & 7) << 4;                                                    \
        short8 q0_ = *(const short8*)&lq[(row_ * 128 + ((lg * 16) ^ cb_)) >> 1];      \
        short8 q1_ = *(const short8*)&lq[(row_ * 128 + ((64 + lg * 16) ^ cb_)) >> 1]; \
        fx4 t_ = MFMA(af0, q0_, z_);                                                  \
        acc_[j_] = MFMA(af1, q1_, t_);                                                \
      }                                                                               \
      _Pragma("unroll") for (int j_ = 0; j_ < 4; ++j_) {                              \
        ushortx4 o_;                                                                  \
        _Pragma("unroll") for (int r_ = 0; r_ < 4; ++r_) o_[r_] = f2bf(acc_[j_][r_]); \
        *(ushortx4*)&B_all[((size_t)((jh_ * 4 + j_) * 16 + l15) * 1024 + t) * 1024 + sb_ + lg * 4] = o_; \
      }                                                                               \
    }                                                                                 \
  }

#pragma unroll
  for (int cc = 0; cc < 4; ++cc) {
    int c = cc * 2;
    short8 af0, af1;
    CVT(af0, af1, a0, a1, a2, a3)
    if (cc < 3) LOADSET(a0, a1, a2, a3, c + 2)
    COMPUTE(af0, af1, c)
    short8 bf0, bf1;
    CVT(bf0, bf1, b0, b1, b2, b3)
    if (cc < 3) LOADSET(b0, b1, b2, b3, c + 3)
    COMPUTE(bf0, bf1, c + 1)
  }
#undef LOADSET
#undef CVT
#undef COMPUTE
}

// ---------------- flash attention v2 ----------------
// block = 128 t-rows x one bh; 4 waves x (2 t-tiles of 16 rows). s-steps of 64.
// lVt: linear [d][s] with unit-swizzle (s>>3)^((d>>3)&7) -> conflict-free writes+reads.
// T14: next K/V tile loaded to regs during compute, written to LDS after barrier.
__global__ __launch_bounds__(256, 4) void attn_kernel(const ushort_t* __restrict__ q,
                                                      const ushort_t* __restrict__ k,
                                                      const ushort_t* __restrict__ v,
                                                      const ushort_t* __restrict__ B_all,
                                                      const unsigned* __restrict__ mbits,
                                                      ushort_t* __restrict__ out) {
  __shared__ ushort_t lK[64][72];
  __shared__ ushort_t lVt[4096];  // [d=64][s=64], elem = d*64 + ((s>>3)^((d>>3)&7))*8 + (s&7)
  __shared__ ushort_t lP[4][16][72];
  int bh = blockIdx.y, b = bh >> 4, h = bh & 15;
  int t0 = blockIdx.x * 128;
  int tid = threadIdx.x, wave = tid >> 6, lane = tid & 63, l15 = lane & 15, lg = lane >> 4;
  int twA = t0 + wave * 16, twB = twA + 64;
  short8 qfA[2], qfB[2];
#pragma unroll
  for (int ks = 0; ks < 2; ++ks) {
    qfA[ks] = *(const short8*)&q[((size_t)(b * 1024 + twA + l15)) * 1024 + h * 64 + ks * 32 + lg * 8];
    qfB[ks] = *(const short8*)&q[((size_t)(b * 1024 + twB + l15)) * 1024 + h * 64 + ks * 32 + lg * 8];
  }
  fx4 oA[4] = {}, oB[4] = {};
  float mrunA = -INFINITY, lsumA = 0.f, mrunB = -INFINITY, lsumB = 0.f;
  const unsigned* mrowA = &mbits[((size_t)b * 1024 + twA + l15) * 32];
  const unsigned* mrowB = &mbits[((size_t)b * 1024 + twB + l15) * 32];
  size_t ballA = ((size_t)bh * 1024 + twA + l15) * 1024;
  size_t ballB = ((size_t)bh * 1024 + twB + l15) * 1024;

  int rs = tid >> 3, c8 = (tid & 7) * 8;  // staging: rows rs, rs+32; 8 cols from c8
  const ushort_t* kbase = &k[((size_t)(b * 1024) + rs) * 1024 + h * 64 + c8];
  const ushort_t* vbase = &v[((size_t)(b * 1024) + rs) * 1024 + h * 64 + c8];
  ushort8 kr0 = *(const ushort8*)(kbase);
  ushort8 kr1 = *(const ushort8*)(kbase + 32 * 1024);
  ushort8 vr0 = *(const ushort8*)(vbase);
  ushort8 vr1 = *(const ushort8*)(vbase + 32 * 1024);

#define COMPUTE_TILE(QF, B4, WB, MRUN, LSUM, OACC)                                 \
  {                                                                                \
    float p_[16];                                                                  \
    float mt_ = -INFINITY;                                                         \
    _Pragma("unroll") for (int mf = 0; mf < 4; ++mf) {                             \
      fx4 c4_ = {};                                                                \
      _Pragma("unroll") for (int ks = 0; ks < 2; ++ks) {                           \
        short8 kf_ = *(const short8*)&lK[mf * 16 + l15][ks * 32 + lg * 8];         \
        c4_ = MFMA(kf_, QF[ks], c4_);                                              \
      }                                                                            \
      _Pragma("unroll") for (int r = 0; r < 4; ++r) {                              \
        float sv_ = (c4_[r] + bf2f(B4[mf][r])) * 0.125f;                           \
        int sl_ = mf * 16 + lg * 4 + r;                                            \
        if (!((WB >> sl_) & 1ull)) sv_ = -INFINITY;                                \
        p_[mf * 4 + r] = sv_;                                                      \
        mt_ = fmaxf(mt_, sv_);                                                     \
      }                                                                            \
    }                                                                              \
    mt_ = fmaxf(mt_, __shfl_xor(mt_, 16));                                         \
    mt_ = fmaxf(mt_, __shfl_xor(mt_, 32));                                         \
    float mnew_ = fmaxf(MRUN, mt_);                                                \
    float alpha_ = (mnew_ == -INFINITY) ? 1.f : __expf(MRUN - mnew_);              \
    MRUN = mnew_;                                                                  \
    float ps_ = 0.f;                                                               \
    _Pragma("unroll") for (int i = 0; i < 16; ++i) {                               \
      float pv_ = (mnew_ == -INFINITY) ? 0.f : __expf(p_[i] - mnew_);              \
      p_[i] = pv_;                                                                 \
      ps_ += pv_;                                                                  \
    }                                                                              \
    ps_ += __shfl_xor(ps_, 16);                                                    \
    ps_ += __shfl_xor(ps_, 32);                                                    \
    LSUM = LSUM * alpha_ + ps_;                                                    \
    _Pragma("unroll") for (int mf = 0; mf < 4; ++mf) {                             \
      ushortx4 pk4_;                                                               \
      _Pragma("unroll") for (int r = 0; r < 4; ++r) pk4_[r] = f2bf(p_[mf * 4 + r]);\
      *(ushortx4*)&lP[wave][l15][mf * 16 + lg * 4] = pk4_;                         \
    }                                                                              \
    float aw_[4];                                                                  \
    _Pragma("unroll") for (int r = 0; r < 4; ++r) aw_[r] = __shfl(alpha_, lg * 4 + r); \
    _Pragma("unroll") for (int nf = 0; nf < 4; ++nf)                               \
      _Pragma("unroll") for (int r = 0; r < 4; ++r) OACC[nf][r] *= aw_[r];         \
    _Pragma("unroll") for (int ks = 0; ks < 2; ++ks) {                             \
      short8 pf_ = *(const short8*)&lP[wave][l15][ks * 32 + lg * 8];               \
      _Pragma("unroll") for (int nf = 0; nf < 4; ++nf) {                           \
        int d_ = nf * 16 + l15;                                                    \
        short8 vf_ = *(const short8*)&lVt[d_ * 64 + (((ks * 4 + lg) ^ ((d_ >> 3) & 7)) * 8)]; \
        OACC[nf] = MFMA(pf_, vf_, OACC[nf]);                                       \
      }                                                                            \
    }                                                                              \
  }

  for (int s0 = 0; s0 < 1024; s0 += 64) {
    __syncthreads();
    *(ushort8*)&lK[rs][c8] = kr0;
    *(ushort8*)&lK[rs + 32][c8] = kr1;
#pragma unroll
    for (int j = 0; j < 8; ++j) {
      int d0 = c8 + j;
      int sz0 = ((rs >> 3) ^ ((d0 >> 3) & 7)) * 8 + (rs & 7);
      int rs1 = rs + 32;
      int sz1 = ((rs1 >> 3) ^ ((d0 >> 3) & 7)) * 8 + (rs1 & 7);
      lVt[d0 * 64 + sz0] = vr0[j];
      lVt[d0 * 64 + sz1] = vr1[j];
    }
    __syncthreads();
    if (s0 + 64 < 1024) {
      size_t off = (size_t)(s0 + 64) * 1024;
      kr0 = *(const ushort8*)(kbase + off);
      kr1 = *(const ushort8*)(kbase + off + 32 * 1024);
      vr0 = *(const ushort8*)(vbase + off);
      vr1 = *(const ushort8*)(vbase + off + 32 * 1024);
    }
    // hoist B_all + mask-bit loads for both tiles
    ushortx4 b4A[4], b4B[4];
#pragma unroll
    for (int mf = 0; mf < 4; ++mf) {
      b4A[mf] = *(const ushortx4*)&B_all[ballA + s0 + mf * 16 + lg * 4];
      b4B[mf] = *(const ushortx4*)&B_all[ballB + s0 + mf * 16 + lg * 4];
    }
    uint2 mwA = *(const uint2*)&mrowA[s0 >> 5];
    uint2 mwB = *(const uint2*)&mrowB[s0 >> 5];
    unsigned long long wbA = ((unsigned long long)mwA.y << 32) | mwA.x;
    unsigned long long wbB = ((unsigned long long)mwB.y << 32) | mwB.x;
    COMPUTE_TILE(qfA, b4A, wbA, mrunA, lsumA, oA)
    COMPUTE_TILE(qfB, b4B, wbB, mrunB, lsumB, oB)
  }
#undef COMPUTE_TILE
  {
    float rlA = (lsumA > 0.f) ? 1.f / lsumA : 0.f;
    float rlB = (lsumB > 0.f) ? 1.f / lsumB : 0.f;
    float rwA[4], rwB[4];
#pragma unroll
    for (int r = 0; r < 4; ++r) {
      rwA[r] = __shfl(rlA, lg * 4 + r);
      rwB[r] = __shfl(rlB, lg * 4 + r);
    }
#pragma unroll
    for (int nf = 0; nf < 4; ++nf)
#pragma unroll
      for (int r = 0; r < 4; ++r) {
        out[((size_t)(b * 1024 + twA + lg * 4 + r)) * 1024 + h * 64 + nf * 16 + l15] =
            f2bf(oA[nf][r] * rwA[r]);
        out[((size_t)(b * 1024 + twB + lg * 4 + r)) * 1024 + h * 64 + nf * 16 + l15] =
            f2bf(oB[nf][r] * rwB[r]);
      }
  }
}

extern "C" void kernel_launch(void* const* d_in, const int* in_sizes, int n_in, void* d_out,
                              int out_size, void* d_ws, size_t ws_size, hipStream_t stream) {
  (void)in_sizes; (void)n_in; (void)out_size; (void)ws_size;
  const float* x = (const float*)d_in[0];
  const float* pos_k = (const float*)d_in[1];
  const int* mask = (const int*)d_in[2];
  const float* ln_scale = (const float*)d_in[3];
  const float* ln_bias = (const float*)d_in[4];
  const float* wq = (const float*)d_in[5];
  const float* bq = (const float*)d_in[6];
  const float* wk = (const float*)d_in[7];
  const float* bk = (const float*)d_in[8];
  const float* wv = (const float*)d_in[9];
  const float* bv = (const float*)d_in[10];
  const float* wo = (const float*)d_in[11];
  const float* bo = (const float*)d_in[12];
  float* out = (float*)d_out;
  char* ws = (char*)d_ws;
  const size_t MB = 1ull << 20;
  ushort_t* xn = (ushort_t*)(ws + 0 * MB);   // 16 MB; region reused for mbits after QKV
  ushort_t* qb = (ushort_t*)(ws + 16 * MB);
  ushort_t* kb = (ushort_t*)(ws + 32 * MB);
  ushort_t* vb = (ushort_t*)(ws + 48 * MB);
  ushort_t* ao = (ushort_t*)(ws + 64 * MB);
  ushort_t* wqb = (ushort_t*)(ws + 80 * MB);
  ushort_t* wkb = (ushort_t*)(ws + 82 * MB);
  ushort_t* wvb = (ushort_t*)(ws + 84 * MB);
  ushort_t* wob = (ushort_t*)(ws + 86 * MB);
  ushort_t* ball = (ushort_t*)(ws + 88 * MB);  // 256 MB -> ws >= 344 MB
  unsigned* mbits = (unsigned*)(ws + 0 * MB);  // 1 MB, reuses xn region (dead after QKV)

  cvt4_kernel<<<4096, 256, 0, stream>>>(wq, wk, wv, wo, wqb, wkb, wvb, wob);
  ln_kernel<<<8192, 256, 0, stream>>>(x, ln_scale, ln_bias, xn);
  dim3 gg(8, 64);
  gemm_bt<0><<<gg, 256, 0, stream>>>(xn, wqb, bq, qb, 8192, 1024, 1024);
  gemm_bt<0><<<gg, 256, 0, stream>>>(xn, wkb, bk, kb, 8192, 1024, 1024);
  gemm_bt<0><<<gg, 256, 0, stream>>>(xn, wvb, bv, vb, 8192, 1024, 1024);
  maskpack_kernel<<<8192, 256, 0, stream>>>(mask, mbits);  // after QKV: xn region now free
  ball_kernel<<<dim3(2, 1024), 256, 0, stream>>>(qb, pos_k, ball);
  attn_kernel<<<dim3(8, 128), 256, 0, stream>>>(qb, kb, vb, ball, mbits, ao);
  gemm_bt<1><<<gg, 256, 0, stream>>>(ao, wob, bo, out, 8192, 1024, 1024);
}

// Round 6
// 488.595 us; speedup vs baseline: 2.1774x; 2.1774x over previous
//
#include <hip/hip_runtime.h>
#include <hip/hip_bf16.h>

typedef unsigned short ushort_t;
typedef short short8 __attribute__((ext_vector_type(8)));
typedef unsigned short ushort8 __attribute__((ext_vector_type(8)));
typedef unsigned short ushortx4 __attribute__((ext_vector_type(4)));
typedef float fx4 __attribute__((ext_vector_type(4)));
typedef int ix4 __attribute__((ext_vector_type(4)));

#define MFMA(a, b, c) __builtin_amdgcn_mfma_f32_16x16x32_bf16((a), (b), (c), 0, 0, 0)

__device__ __forceinline__ ushort_t f2bf(float f) {
  __hip_bfloat16 h = __float2bfloat16(f);
  return *(ushort_t*)&h;
}
__device__ __forceinline__ float bf2f(ushort_t h) {
  union { unsigned u; float f; } c; c.u = ((unsigned)h) << 16;
  return c.f;
}
__device__ __forceinline__ void gload16(const ushort_t* g, ushort_t* l) {
  __builtin_amdgcn_global_load_lds((const __attribute__((address_space(1))) void*)g,
                                   (__attribute__((address_space(3))) void*)l, 16, 0, 0);
}

// ---------------- f32 -> bf16 convert for the 4 weight matrices ----------------
__global__ __launch_bounds__(256) void cvt4_kernel(const float* __restrict__ s0,
                                                   const float* __restrict__ s1,
                                                   const float* __restrict__ s2,
                                                   const float* __restrict__ s3,
                                                   ushort_t* __restrict__ d0,
                                                   ushort_t* __restrict__ d1,
                                                   ushort_t* __restrict__ d2,
                                                   ushort_t* __restrict__ d3) {
  int bi = blockIdx.x;
  const float* src = (bi < 1024) ? s0 : (bi < 2048) ? s1 : (bi < 3072) ? s2 : s3;
  ushort_t* dst = (bi < 1024) ? d0 : (bi < 2048) ? d1 : (bi < 3072) ? d2 : d3;
  int i = (bi & 1023) * 256 + threadIdx.x;
  fx4 v = *(const fx4*)&src[(size_t)i * 4];
  ushortx4 o;
#pragma unroll
  for (int j = 0; j < 4; ++j) o[j] = f2bf(v[j]);
  *(ushortx4*)&dst[(size_t)i * 4] = o;
}

// ---------------- LayerNorm: x (f32, row=1024) -> xn (bf16) ----------------
__global__ __launch_bounds__(256) void ln_kernel(const float* __restrict__ x,
                                                 const float* __restrict__ sc,
                                                 const float* __restrict__ bi,
                                                 ushort_t* __restrict__ xn) {
  __shared__ float red[8];
  int row = blockIdx.x, tid = threadIdx.x;
  const float* xr = x + (size_t)row * 1024;
  fx4 v = *(const fx4*)&xr[tid * 4];
  float s = v[0] + v[1] + v[2] + v[3];
  float s2 = v[0] * v[0] + v[1] * v[1] + v[2] * v[2] + v[3] * v[3];
#pragma unroll
  for (int m = 32; m >= 1; m >>= 1) {
    s += __shfl_xor(s, m);
    s2 += __shfl_xor(s2, m);
  }
  int wave = tid >> 6;
  if ((tid & 63) == 0) { red[wave * 2] = s; red[wave * 2 + 1] = s2; }
  __syncthreads();
  s = red[0] + red[2] + red[4] + red[6];
  s2 = red[1] + red[3] + red[5] + red[7];
  float mu = s * (1.f / 1024.f);
  float var = s2 * (1.f / 1024.f) - mu * mu;
  float rs = rsqrtf(var + 1e-5f);
  fx4 scv = *(const fx4*)&sc[tid * 4];
  fx4 biv = *(const fx4*)&bi[tid * 4];
  ushortx4 o;
#pragma unroll
  for (int j = 0; j < 4; ++j) o[j] = f2bf((v[j] - mu) * rs * scv[j] + biv[j]);
  *(ushortx4*)&xn[(size_t)row * 1024 + tid * 4] = o;
}

// ---------------- mask (int32) -> 1 bit per (b,t,s) ----------------
__global__ __launch_bounds__(256) void maskpack_kernel(const int* __restrict__ mask,
                                                       unsigned* __restrict__ bits) {
  __shared__ unsigned char nib[256];
  int row = blockIdx.x, tid = threadIdx.x;
  ix4 m = *(const ix4*)&mask[(size_t)row * 1024 + tid * 4];
  nib[tid] = (unsigned char)((m[0] != 0 ? 1 : 0) | (m[1] != 0 ? 2 : 0) |
                             (m[2] != 0 ? 4 : 0) | (m[3] != 0 ? 8 : 0));
  __syncthreads();
  if (tid < 32) {
    unsigned w = 0;
#pragma unroll
    for (int j = 0; j < 8; ++j) w |= ((unsigned)nib[tid * 8 + j]) << (j * 4);
    bits[(size_t)row * 32 + tid] = w;
  }
}

// ---------------- GEMM: C[M][N] = A[M][K] @ B[N][K]^T + bias ----------------
template <int F32OUT>
__global__ __launch_bounds__(256) void gemm_bt(const ushort_t* __restrict__ A,
                                               const ushort_t* __restrict__ B,
                                               const float* __restrict__ bias, void* C,
                                               int M, int N, int K) {
  __shared__ ushort_t lA[4096];  // [128][32] linear
  __shared__ ushort_t lB[4096];
  int bm = blockIdx.y * 128, bn = blockIdx.x * 128;
  int tid = threadIdx.x;
  int wave = tid >> 6, lane = tid & 63;
  int wm = (wave >> 1) * 64, wn = (wave & 1) * 64;
  int l15 = lane & 15, lg = lane >> 4;
  int r0 = tid >> 2, c0 = (tid & 3) * 8;
  int g1 = 256 + tid, r1 = g1 >> 2, c1 = (g1 & 3) * 8;
  int lb0 = (wave * 64) * 8;
  int lb1 = (256 + wave * 64) * 8;
  fx4 acc[4][4] = {};
  for (int k0 = 0; k0 < K; k0 += 32) {
    __syncthreads();
    gload16(&A[(size_t)(bm + r0) * K + k0 + c0], &lA[lb0]);
    gload16(&A[(size_t)(bm + r1) * K + k0 + c1], &lA[lb1]);
    gload16(&B[(size_t)(bn + r0) * K + k0 + c0], &lB[lb0]);
    gload16(&B[(size_t)(bn + r1) * K + k0 + c1], &lB[lb1]);
    __syncthreads();
    short8 af[4], bf[4];
#pragma unroll
    for (int i = 0; i < 4; ++i) af[i] = *(const short8*)&lA[(wm + i * 16 + l15) * 32 + lg * 8];
#pragma unroll
    for (int i = 0; i < 4; ++i) bf[i] = *(const short8*)&lB[(wn + i * 16 + l15) * 32 + lg * 8];
#pragma unroll
    for (int i = 0; i < 4; ++i)
#pragma unroll
      for (int j = 0; j < 4; ++j) acc[i][j] = MFMA(af[i], bf[j], acc[i][j]);
  }
#pragma unroll
  for (int j = 0; j < 4; ++j) {
    int n = bn + wn + j * 16 + l15;
    float bv = bias[n];
#pragma unroll
    for (int i = 0; i < 4; ++i) {
      int mr = bm + wm + i * 16 + lg * 4;
#pragma unroll
      for (int r = 0; r < 4; ++r) {
        float val = acc[i][j][r] + bv;
        if (F32OUT)
          ((float*)C)[(size_t)(mr + r) * N + n] = val;
        else
          ((ushort_t*)C)[(size_t)(mr + r) * N + n] = f2bf(val);
      }
    }
  }
}

// ---------------- B_all[bh][t][s] = sum_d q[b,t,h*64+d] * pos_k[t,s,d] ----------------
// v5: v4 + sched_barrier(0) pins so the 2-deep pos_k register pipeline can't be
// sunk by the scheduler (r2/r3 lesson: compiler sank prefetch loads to their use).
__global__ __launch_bounds__(256, 4) void ball_kernel(const ushort_t* __restrict__ q,
                                                      const float* __restrict__ pos_k,
                                                      ushort_t* __restrict__ B_all) {
  __shared__ ushort_t lq[128 * 64];  // rows of 128 B, col-byte ^= (row&7)<<4
  int t = blockIdx.y, sx = blockIdx.x;
  int tid = threadIdx.x, wave = tid >> 6, lane = tid & 63, l15 = lane & 15, lg = lane >> 4;

  const float* pk = pos_k + (size_t)t * 65536;
  int sw = sx * 512 + wave * 128;
  const float* base = pk + (size_t)(sw + l15) * 64 + lg * 8;

  fx4 a0, a1, a2, a3, b0, b1, b2, b3;
#define LOADSET(v0, v1, v2, v3, c)                \
  {                                               \
    const float* p_ = base + (size_t)(c) * 1024;  \
    v0 = *(const fx4*)p_;                         \
    v1 = *(const fx4*)(p_ + 4);                   \
    v2 = *(const fx4*)(p_ + 32);                  \
    v3 = *(const fx4*)(p_ + 36);                  \
  }
  LOADSET(a0, a1, a2, a3, 0)
  LOADSET(b0, b1, b2, b3, 1)

  // stage q[t]: 128 bh-rows x 64 bf16 (16 KB), swizzled
#pragma unroll
  for (int it = 0; it < 4; ++it) {
    int u = tid + it * 256;           // 0..1023 16B-units
    int row = u >> 3, cu = u & 7;     // row=bh, cu=16B col unit
    ushort8 vv = *(const ushort8*)&q[((size_t)((row >> 4) * 1024 + t)) * 1024 + (row & 15) * 64 + cu * 8];
    *(ushort8*)&lq[(row * 128 + ((cu * 16) ^ ((row & 7) << 4))) >> 1] = vv;
  }
  __syncthreads();

#define CVT(af0, af1, v0, v1, v2, v3)                              \
  {                                                                \
    _Pragma("unroll") for (int j_ = 0; j_ < 4; ++j_) {             \
      af0[j_] = (short)f2bf(v0[j_]); af0[j_ + 4] = (short)f2bf(v1[j_]); \
      af1[j_] = (short)f2bf(v2[j_]); af1[j_ + 4] = (short)f2bf(v3[j_]); \
    }                                                              \
  }

#define COMPUTE(af0, af1, c)                                                          \
  {                                                                                   \
    int sb_ = sw + (c) * 16;                                                          \
    fx4 z_ = {};                                                                      \
    _Pragma("unroll") for (int jh_ = 0; jh_ < 2; ++jh_) {                             \
      fx4 acc_[4];                                                                    \
      _Pragma("unroll") for (int j_ = 0; j_ < 4; ++j_) {                              \
        int row_ = (jh_ * 4 + j_) * 16 + l15;                                         \
        int cb_ = (row_ & 7) << 4;                                                    \
        short8 q0_ = *(const short8*)&lq[(row_ * 128 + ((lg * 16) ^ cb_)) >> 1];      \
        short8 q1_ = *(const short8*)&lq[(row_ * 128 + ((64 + lg * 16) ^ cb_)) >> 1]; \
        fx4 t_ = MFMA(af0, q0_, z_);                                                  \
        acc_[j_] = MFMA(af1, q1_, t_);                                                \
      }                                                                               \
      _Pragma("unroll") for (int j_ = 0; j_ < 4; ++j_) {                              \
        ushortx4 o_;                                                                  \
        _Pragma("unroll") for (int r_ = 0; r_ < 4; ++r_) o_[r_] = f2bf(acc_[j_][r_]); \
        *(ushortx4*)&B_all[((size_t)((jh_ * 4 + j_) * 16 + l15) * 1024 + t) * 1024 + sb_ + lg * 4] = o_; \
      }                                                                               \
    }                                                                                 \
  }

#pragma unroll
  for (int cc = 0; cc < 4; ++cc) {
    int c = cc * 2;
    short8 af0, af1;
    CVT(af0, af1, a0, a1, a2, a3)
    if (cc < 3) LOADSET(a0, a1, a2, a3, c + 2)
    __builtin_amdgcn_sched_barrier(0);
    COMPUTE(af0, af1, c)
    short8 bf0, bf1;
    CVT(bf0, bf1, b0, b1, b2, b3)
    if (cc < 3) LOADSET(b0, b1, b2, b3, c + 3)
    __builtin_amdgcn_sched_barrier(0);
    COMPUTE(bf0, bf1, c + 1)
  }
#undef LOADSET
#undef CVT
#undef COMPUTE
}

// ---------------- flash attention v3 (r3 structure + targeted fixes) ----------------
// per (t_blk 64 rows, bh), 4 waves x 16 t-rows. s-steps of 64.
// lVt[d][(s + 8*(d>>3)) & 63], row stride 72 -> conflict-free transposed writes,
// balanced reads. T14 reg-prefetch of next K/V pinned with sched_barrier(0).
__global__ __launch_bounds__(256) void attn_kernel(const ushort_t* __restrict__ q,
                                                   const ushort_t* __restrict__ k,
                                                   const ushort_t* __restrict__ v,
                                                   const ushort_t* __restrict__ B_all,
                                                   const unsigned* __restrict__ mbits,
                                                   ushort_t* __restrict__ out) {
  __shared__ ushort_t lK[64][72];
  __shared__ ushort_t lVt[64][72];
  __shared__ ushort_t lP[4][16][72];
  int bh = blockIdx.y, b = bh >> 4, h = bh & 15;
  int t0 = blockIdx.x * 64;
  int tid = threadIdx.x, wave = tid >> 6, lane = tid & 63, l15 = lane & 15, lg = lane >> 4;
  int tw = t0 + wave * 16;
  short8 qf[2];
#pragma unroll
  for (int ks = 0; ks < 2; ++ks)
    qf[ks] = *(const short8*)&q[((size_t)(b * 1024 + tw + l15)) * 1024 + h * 64 + ks * 32 + lg * 8];
  fx4 o[4] = {};
  float mrun = -INFINITY, lsum = 0.f;
  int trow = tw + l15;
  const unsigned* mrow = &mbits[((size_t)b * 1024 + trow) * 32];
  size_t ballrow = ((size_t)bh * 1024 + trow) * 1024;

  int rs = tid >> 3, c8g = tid & 7, c8 = c8g * 8;  // staging: rows rs, rs+32
  const ushort_t* kbase = &k[((size_t)(b * 1024) + rs) * 1024 + h * 64 + c8];
  const ushort_t* vbase = &v[((size_t)(b * 1024) + rs) * 1024 + h * 64 + c8];
  ushort8 kr0 = *(const ushort8*)(kbase);
  ushort8 kr1 = *(const ushort8*)(kbase + 32 * 1024);
  ushort8 vr0 = *(const ushort8*)(vbase);
  ushort8 vr1 = *(const ushort8*)(vbase + 32 * 1024);
  int vs0 = (rs + 8 * c8g) & 63;        // rotated s-slot for row rs
  int vs1 = (rs + 32 + 8 * c8g) & 63;   // rotated s-slot for row rs+32

  for (int s0 = 0; s0 < 1024; s0 += 64) {
    __syncthreads();
    *(ushort8*)&lK[rs][c8] = kr0;
    *(ushort8*)&lK[rs + 32][c8] = kr1;
#pragma unroll
    for (int j = 0; j < 8; ++j) {
      lVt[c8 + j][vs0] = vr0[j];
      lVt[c8 + j][vs1] = vr1[j];
    }
    __syncthreads();
    if (s0 + 64 < 1024) {
      size_t off = (size_t)(s0 + 64) * 1024;
      kr0 = *(const ushort8*)(kbase + off);
      kr1 = *(const ushort8*)(kbase + off + 32 * 1024);
      vr0 = *(const ushort8*)(vbase + off);
      vr1 = *(const ushort8*)(vbase + off + 32 * 1024);
    }
    __builtin_amdgcn_sched_barrier(0);
    // hoisted B_all + mask-bit loads
    ushortx4 b4[4];
#pragma unroll
    for (int mf = 0; mf < 4; ++mf)
      b4[mf] = *(const ushortx4*)&B_all[ballrow + s0 + mf * 16 + lg * 4];
    uint2 mw = *(const uint2*)&mrow[s0 >> 5];
    unsigned long long wb = ((unsigned long long)mw.y << 32) | mw.x;
    __builtin_amdgcn_sched_barrier(0);
    // S^T tile: mfma(A=K[s,d], B=Q[t,d]) -> D[s][t]
    fx4 st[4];
#pragma unroll
    for (int mf = 0; mf < 4; ++mf) {
      fx4 c4 = {};
#pragma unroll
      for (int ks = 0; ks < 2; ++ks) {
        short8 kf = *(const short8*)&lK[mf * 16 + l15][ks * 32 + lg * 8];
        c4 = MFMA(kf, qf[ks], c4);
      }
      st[mf] = c4;
    }
    float p[16];
    float mt = -INFINITY;
#pragma unroll
    for (int mf = 0; mf < 4; ++mf) {
#pragma unroll
      for (int r = 0; r < 4; ++r) {
        float sv = (st[mf][r] + bf2f(b4[mf][r])) * 0.125f;
        int sl = mf * 16 + lg * 4 + r;
        if (!((wb >> sl) & 1ull)) sv = -INFINITY;
        p[mf * 4 + r] = sv;
        mt = fmaxf(mt, sv);
      }
    }
    mt = fmaxf(mt, __shfl_xor(mt, 16));
    mt = fmaxf(mt, __shfl_xor(mt, 32));
    float mnew = fmaxf(mrun, mt);
    float alpha = (mnew == -INFINITY) ? 1.f : __expf(mrun - mnew);
    mrun = mnew;
    float ps = 0.f;
#pragma unroll
    for (int i = 0; i < 16; ++i) {
      float pv = (mnew == -INFINITY) ? 0.f : __expf(p[i] - mnew);
      p[i] = pv;
      ps += pv;
    }
    ps += __shfl_xor(ps, 16);
    ps += __shfl_xor(ps, 32);
    lsum = lsum * alpha + ps;
#pragma unroll
    for (int mf = 0; mf < 4; ++mf) {
      ushortx4 pk4;
#pragma unroll
      for (int r = 0; r < 4; ++r) pk4[r] = f2bf(p[mf * 4 + r]);
      *(ushortx4*)&lP[wave][l15][mf * 16 + lg * 4] = pk4;
    }
    float aw[4];
#pragma unroll
    for (int r = 0; r < 4; ++r) aw[r] = __shfl(alpha, lg * 4 + r);
#pragma unroll
    for (int nf = 0; nf < 4; ++nf)
#pragma unroll
      for (int r = 0; r < 4; ++r) o[nf][r] *= aw[r];
    // PV: mfma(A=P[t,s], B=V[s,d]) -> D[t][d]
#pragma unroll
    for (int ks = 0; ks < 2; ++ks) {
      short8 pf = *(const short8*)&lP[wave][l15][ks * 32 + lg * 8];
#pragma unroll
      for (int nf = 0; nf < 4; ++nf) {
        int d_ = nf * 16 + l15;
        int sb_ = (ks * 32 + lg * 8 + 8 * (d_ >> 3)) & 63;
        short8 vf = *(const short8*)&lVt[d_][sb_];
        o[nf] = MFMA(pf, vf, o[nf]);
      }
    }
  }
  float rl = (lsum > 0.f) ? 1.f / lsum : 0.f;
  float rw[4];
#pragma unroll
  for (int r = 0; r < 4; ++r) rw[r] = __shfl(rl, lg * 4 + r);
#pragma unroll
  for (int nf = 0; nf < 4; ++nf)
#pragma unroll
    for (int r = 0; r < 4; ++r) {
      float val = o[nf][r] * rw[r];
      out[((size_t)(b * 1024 + tw + lg * 4 + r)) * 1024 + h * 64 + nf * 16 + l15] = f2bf(val);
    }
}

extern "C" void kernel_launch(void* const* d_in, const int* in_sizes, int n_in, void* d_out,
                              int out_size, void* d_ws, size_t ws_size, hipStream_t stream) {
  (void)in_sizes; (void)n_in; (void)out_size; (void)ws_size;
  const float* x = (const float*)d_in[0];
  const float* pos_k = (const float*)d_in[1];
  const int* mask = (const int*)d_in[2];
  const float* ln_scale = (const float*)d_in[3];
  const float* ln_bias = (const float*)d_in[4];
  const float* wq = (const float*)d_in[5];
  const float* bq = (const float*)d_in[6];
  const float* wk = (const float*)d_in[7];
  const float* bk = (const float*)d_in[8];
  const float* wv = (const float*)d_in[9];
  const float* bv = (const float*)d_in[10];
  const float* wo = (const float*)d_in[11];
  const float* bo = (const float*)d_in[12];
  float* out = (float*)d_out;
  char* ws = (char*)d_ws;
  const size_t MB = 1ull << 20;
  ushort_t* xn = (ushort_t*)(ws + 0 * MB);   // 16 MB; region reused for mbits after QKV
  ushort_t* qb = (ushort_t*)(ws + 16 * MB);
  ushort_t* kb = (ushort_t*)(ws + 32 * MB);
  ushort_t* vb = (ushort_t*)(ws + 48 * MB);
  ushort_t* ao = (ushort_t*)(ws + 64 * MB);
  ushort_t* wqb = (ushort_t*)(ws + 80 * MB);
  ushort_t* wkb = (ushort_t*)(ws + 82 * MB);
  ushort_t* wvb = (ushort_t*)(ws + 84 * MB);
  ushort_t* wob = (ushort_t*)(ws + 86 * MB);
  ushort_t* ball = (ushort_t*)(ws + 88 * MB);  // 256 MB -> ws >= 344 MB
  unsigned* mbits = (unsigned*)(ws + 0 * MB);  // 1 MB, reuses xn region (dead after QKV)

  cvt4_kernel<<<4096, 256, 0, stream>>>(wq, wk, wv, wo, wqb, wkb, wvb, wob);
  ln_kernel<<<8192, 256, 0, stream>>>(x, ln_scale, ln_bias, xn);
  dim3 gg(8, 64);
  gemm_bt<0><<<gg, 256, 0, stream>>>(xn, wqb, bq, qb, 8192, 1024, 1024);
  gemm_bt<0><<<gg, 256, 0, stream>>>(xn, wkb, bk, kb, 8192, 1024, 1024);
  gemm_bt<0><<<gg, 256, 0, stream>>>(xn, wvb, bv, vb, 8192, 1024, 1024);
  maskpack_kernel<<<8192, 256, 0, stream>>>(mask, mbits);  // after QKV: xn region now free
  ball_kernel<<<dim3(2, 1024), 256, 0, stream>>>(qb, pos_k, ball);
  attn_kernel<<<dim3(16, 128), 256, 0, stream>>>(qb, kb, vb, ball, mbits, ao);
  gemm_bt<1><<<gg, 256, 0, stream>>>(ao, wob, bo, out, 8192, 1024, 1024);
}

// Round 7
// 436.130 us; speedup vs baseline: 2.4394x; 1.1203x over previous
//
#include <hip/hip_runtime.h>
#include <hip/hip_bf16.h>

typedef unsigned short ushort_t;
typedef short short8 __attribute__((ext_vector_type(8)));
typedef unsigned short ushort8 __attribute__((ext_vector_type(8)));
typedef unsigned short ushortx4 __attribute__((ext_vector_type(4)));
typedef float fx4 __attribute__((ext_vector_type(4)));
typedef int ix4 __attribute__((ext_vector_type(4)));

#define MFMA(a, b, c) __builtin_amdgcn_mfma_f32_16x16x32_bf16((a), (b), (c), 0, 0, 0)

__device__ __forceinline__ ushort_t f2bf(float f) {
  __hip_bfloat16 h = __float2bfloat16(f);
  return *(ushort_t*)&h;
}
__device__ __forceinline__ float bf2f(ushort_t h) {
  union { unsigned u; float f; } c; c.u = ((unsigned)h) << 16;
  return c.f;
}
__device__ __forceinline__ void gload16(const ushort_t* g, ushort_t* l) {
  __builtin_amdgcn_global_load_lds((const __attribute__((address_space(1))) void*)g,
                                   (__attribute__((address_space(3))) void*)l, 16, 0, 0);
}

// ---------------- f32 -> bf16 convert for the 4 weight matrices ----------------
__global__ __launch_bounds__(256) void cvt4_kernel(const float* __restrict__ s0,
                                                   const float* __restrict__ s1,
                                                   const float* __restrict__ s2,
                                                   const float* __restrict__ s3,
                                                   ushort_t* __restrict__ d0,
                                                   ushort_t* __restrict__ d1,
                                                   ushort_t* __restrict__ d2,
                                                   ushort_t* __restrict__ d3) {
  int bi = blockIdx.x;
  const float* src = (bi < 1024) ? s0 : (bi < 2048) ? s1 : (bi < 3072) ? s2 : s3;
  ushort_t* dst = (bi < 1024) ? d0 : (bi < 2048) ? d1 : (bi < 3072) ? d2 : d3;
  int i = (bi & 1023) * 256 + threadIdx.x;
  fx4 v = *(const fx4*)&src[(size_t)i * 4];
  ushortx4 o;
#pragma unroll
  for (int j = 0; j < 4; ++j) o[j] = f2bf(v[j]);
  *(ushortx4*)&dst[(size_t)i * 4] = o;
}

// ---------------- LayerNorm: x (f32, row=1024) -> xn (bf16) ----------------
__global__ __launch_bounds__(256) void ln_kernel(const float* __restrict__ x,
                                                 const float* __restrict__ sc,
                                                 const float* __restrict__ bi,
                                                 ushort_t* __restrict__ xn) {
  __shared__ float red[8];
  int row = blockIdx.x, tid = threadIdx.x;
  const float* xr = x + (size_t)row * 1024;
  fx4 v = *(const fx4*)&xr[tid * 4];
  float s = v[0] + v[1] + v[2] + v[3];
  float s2 = v[0] * v[0] + v[1] * v[1] + v[2] * v[2] + v[3] * v[3];
#pragma unroll
  for (int m = 32; m >= 1; m >>= 1) {
    s += __shfl_xor(s, m);
    s2 += __shfl_xor(s2, m);
  }
  int wave = tid >> 6;
  if ((tid & 63) == 0) { red[wave * 2] = s; red[wave * 2 + 1] = s2; }
  __syncthreads();
  s = red[0] + red[2] + red[4] + red[6];
  s2 = red[1] + red[3] + red[5] + red[7];
  float mu = s * (1.f / 1024.f);
  float var = s2 * (1.f / 1024.f) - mu * mu;
  float rs = rsqrtf(var + 1e-5f);
  fx4 scv = *(const fx4*)&sc[tid * 4];
  fx4 biv = *(const fx4*)&bi[tid * 4];
  ushortx4 o;
#pragma unroll
  for (int j = 0; j < 4; ++j) o[j] = f2bf((v[j] - mu) * rs * scv[j] + biv[j]);
  *(ushortx4*)&xn[(size_t)row * 1024 + tid * 4] = o;
}

// ---------------- mask (int32) -> 1 bit per (b,t,s) ----------------
__global__ __launch_bounds__(256) void maskpack_kernel(const int* __restrict__ mask,
                                                       unsigned* __restrict__ bits) {
  __shared__ unsigned char nib[256];
  int row = blockIdx.x, tid = threadIdx.x;
  ix4 m = *(const ix4*)&mask[(size_t)row * 1024 + tid * 4];
  nib[tid] = (unsigned char)((m[0] != 0 ? 1 : 0) | (m[1] != 0 ? 2 : 0) |
                             (m[2] != 0 ? 4 : 0) | (m[3] != 0 ? 8 : 0));
  __syncthreads();
  if (tid < 32) {
    unsigned w = 0;
#pragma unroll
    for (int j = 0; j < 8; ++j) w |= ((unsigned)nib[tid * 8 + j]) << (j * 4);
    bits[(size_t)row * 32 + tid] = w;
  }
}

// ---------------- GEMM: C[M][N] = A[M][K] @ B[N][K]^T + bias ----------------
template <int F32OUT>
__global__ __launch_bounds__(256) void gemm_bt(const ushort_t* __restrict__ A,
                                               const ushort_t* __restrict__ B,
                                               const float* __restrict__ bias, void* C,
                                               int M, int N, int K) {
  __shared__ ushort_t lA[4096];  // [128][32] linear
  __shared__ ushort_t lB[4096];
  int bm = blockIdx.y * 128, bn = blockIdx.x * 128;
  int tid = threadIdx.x;
  int wave = tid >> 6, lane = tid & 63;
  int wm = (wave >> 1) * 64, wn = (wave & 1) * 64;
  int l15 = lane & 15, lg = lane >> 4;
  int r0 = tid >> 2, c0 = (tid & 3) * 8;
  int g1 = 256 + tid, r1 = g1 >> 2, c1 = (g1 & 3) * 8;
  int lb0 = (wave * 64) * 8;
  int lb1 = (256 + wave * 64) * 8;
  fx4 acc[4][4] = {};
  for (int k0 = 0; k0 < K; k0 += 32) {
    __syncthreads();
    gload16(&A[(size_t)(bm + r0) * K + k0 + c0], &lA[lb0]);
    gload16(&A[(size_t)(bm + r1) * K + k0 + c1], &lA[lb1]);
    gload16(&B[(size_t)(bn + r0) * K + k0 + c0], &lB[lb0]);
    gload16(&B[(size_t)(bn + r1) * K + k0 + c1], &lB[lb1]);
    __syncthreads();
    short8 af[4], bf[4];
#pragma unroll
    for (int i = 0; i < 4; ++i) af[i] = *(const short8*)&lA[(wm + i * 16 + l15) * 32 + lg * 8];
#pragma unroll
    for (int i = 0; i < 4; ++i) bf[i] = *(const short8*)&lB[(wn + i * 16 + l15) * 32 + lg * 8];
#pragma unroll
    for (int i = 0; i < 4; ++i)
#pragma unroll
      for (int j = 0; j < 4; ++j) acc[i][j] = MFMA(af[i], bf[j], acc[i][j]);
  }
#pragma unroll
  for (int j = 0; j < 4; ++j) {
    int n = bn + wn + j * 16 + l15;
    float bv = bias[n];
#pragma unroll
    for (int i = 0; i < 4; ++i) {
      int mr = bm + wm + i * 16 + lg * 4;
#pragma unroll
      for (int r = 0; r < 4; ++r) {
        float val = acc[i][j][r] + bv;
        if (F32OUT)
          ((float*)C)[(size_t)(mr + r) * N + n] = val;
        else
          ((ushort_t*)C)[(size_t)(mr + r) * N + n] = f2bf(val);
      }
    }
  }
}

// ---------------- B_all[bh][t][s] = sum_d q[b,t,h*64+d] * pos_k[t,s,d] ----------------
// v6: loop interchange. Hold pos_k fragments for a GROUP of 4 chunks (af0/af1[4]);
// per j (bh block of 16) read q once from LDS, 8 MFMAs over all 4 chunks, then all
// 16 stores of the row's 128 B line issue back-to-back -> L2 assembles full lines
// (fixes r6's 1.64x write amplification). Next group's raw loads issued before the
// j-loop (~800 cy cover), pinned by sched_barrier. launch_bounds(256,3): no spill.
__device__ __forceinline__ void loadset(const float* base, int c, fx4* r) {
  const float* p = base + (size_t)c * 1024;
  r[0] = *(const fx4*)p;
  r[1] = *(const fx4*)(p + 4);
  r[2] = *(const fx4*)(p + 32);
  r[3] = *(const fx4*)(p + 36);
}
__device__ __forceinline__ void cvtset(const fx4* r, short8& f0, short8& f1) {
#pragma unroll
  for (int j = 0; j < 4; ++j) {
    f0[j] = (short)f2bf(r[0][j]); f0[j + 4] = (short)f2bf(r[1][j]);
    f1[j] = (short)f2bf(r[2][j]); f1[j + 4] = (short)f2bf(r[3][j]);
  }
}

__global__ __launch_bounds__(256, 3) void ball_kernel(const ushort_t* __restrict__ q,
                                                      const float* __restrict__ pos_k,
                                                      ushort_t* __restrict__ B_all) {
  __shared__ ushort_t lq[128 * 64];  // rows of 128 B, col-byte ^= (row&7)<<4
  int t = blockIdx.y, sx = blockIdx.x;
  int tid = threadIdx.x, wave = tid >> 6, lane = tid & 63, l15 = lane & 15, lg = lane >> 4;
  const float* pk = pos_k + (size_t)t * 65536;
  int sw = sx * 512 + wave * 128;
  const float* base = pk + (size_t)(sw + l15) * 64 + lg * 8;

  fx4 raw[4][4];
#pragma unroll
  for (int c = 0; c < 4; ++c) loadset(base, c, raw[c]);

  // stage q[t]: 128 bh-rows x 64 bf16 (16 KB), swizzled (covers prologue latency)
#pragma unroll
  for (int it = 0; it < 4; ++it) {
    int u = tid + it * 256;           // 0..1023 16B-units
    int row = u >> 3, cu = u & 7;     // row=bh, cu=16B col unit
    ushort8 vv = *(const ushort8*)&q[((size_t)((row >> 4) * 1024 + t)) * 1024 + (row & 15) * 64 + cu * 8];
    *(ushort8*)&lq[(row * 128 + ((cu * 16) ^ ((row & 7) << 4))) >> 1] = vv;
  }
  __syncthreads();

  short8 af0[4], af1[4];
#pragma unroll
  for (int c = 0; c < 4; ++c) cvtset(raw[c], af0[c], af1[c]);

#pragma unroll
  for (int g = 0; g < 2; ++g) {
    if (g == 0) {
#pragma unroll
      for (int c = 0; c < 4; ++c) loadset(base, 4 + c, raw[c]);
    }
    __builtin_amdgcn_sched_barrier(0);
#pragma unroll
    for (int j = 0; j < 8; ++j) {
      int row_ = j * 16 + l15;
      int cb_ = (row_ & 7) << 4;
      short8 q0 = *(const short8*)&lq[(row_ * 128 + ((lg * 16) ^ cb_)) >> 1];
      short8 q1 = *(const short8*)&lq[(row_ * 128 + ((64 + lg * 16) ^ cb_)) >> 1];
      fx4 z = {};
      size_t rb = ((size_t)row_ << 20) + (size_t)t * 1024 + (size_t)(sw + g * 64);
#pragma unroll
      for (int c = 0; c < 4; ++c) {
        fx4 a = MFMA(af0[c], q0, z);
        a = MFMA(af1[c], q1, a);
        ushortx4 o;
#pragma unroll
        for (int r = 0; r < 4; ++r) o[r] = f2bf(a[r]);
        *(ushortx4*)&B_all[rb + c * 16 + lg * 4] = o;
      }
    }
    __builtin_amdgcn_sched_barrier(0);
    if (g == 0) {
#pragma unroll
      for (int c = 0; c < 4; ++c) cvtset(raw[c], af0[c], af1[c]);
    }
  }
}

// ---------------- flash attention v3 (unchanged from r6: ~170 us) ----------------
__global__ __launch_bounds__(256) void attn_kernel(const ushort_t* __restrict__ q,
                                                   const ushort_t* __restrict__ k,
                                                   const ushort_t* __restrict__ v,
                                                   const ushort_t* __restrict__ B_all,
                                                   const unsigned* __restrict__ mbits,
                                                   ushort_t* __restrict__ out) {
  __shared__ ushort_t lK[64][72];
  __shared__ ushort_t lVt[64][72];
  __shared__ ushort_t lP[4][16][72];
  int bh = blockIdx.y, b = bh >> 4, h = bh & 15;
  int t0 = blockIdx.x * 64;
  int tid = threadIdx.x, wave = tid >> 6, lane = tid & 63, l15 = lane & 15, lg = lane >> 4;
  int tw = t0 + wave * 16;
  short8 qf[2];
#pragma unroll
  for (int ks = 0; ks < 2; ++ks)
    qf[ks] = *(const short8*)&q[((size_t)(b * 1024 + tw + l15)) * 1024 + h * 64 + ks * 32 + lg * 8];
  fx4 o[4] = {};
  float mrun = -INFINITY, lsum = 0.f;
  int trow = tw + l15;
  const unsigned* mrow = &mbits[((size_t)b * 1024 + trow) * 32];
  size_t ballrow = ((size_t)bh * 1024 + trow) * 1024;

  int rs = tid >> 3, c8g = tid & 7, c8 = c8g * 8;  // staging: rows rs, rs+32
  const ushort_t* kbase = &k[((size_t)(b * 1024) + rs) * 1024 + h * 64 + c8];
  const ushort_t* vbase = &v[((size_t)(b * 1024) + rs) * 1024 + h * 64 + c8];
  ushort8 kr0 = *(const ushort8*)(kbase);
  ushort8 kr1 = *(const ushort8*)(kbase + 32 * 1024);
  ushort8 vr0 = *(const ushort8*)(vbase);
  ushort8 vr1 = *(const ushort8*)(vbase + 32 * 1024);
  int vs0 = (rs + 8 * c8g) & 63;        // rotated s-slot for row rs
  int vs1 = (rs + 32 + 8 * c8g) & 63;   // rotated s-slot for row rs+32

  for (int s0 = 0; s0 < 1024; s0 += 64) {
    __syncthreads();
    *(ushort8*)&lK[rs][c8] = kr0;
    *(ushort8*)&lK[rs + 32][c8] = kr1;
#pragma unroll
    for (int j = 0; j < 8; ++j) {
      lVt[c8 + j][vs0] = vr0[j];
      lVt[c8 + j][vs1] = vr1[j];
    }
    __syncthreads();
    if (s0 + 64 < 1024) {
      size_t off = (size_t)(s0 + 64) * 1024;
      kr0 = *(const ushort8*)(kbase + off);
      kr1 = *(const ushort8*)(kbase + off + 32 * 1024);
      vr0 = *(const ushort8*)(vbase + off);
      vr1 = *(const ushort8*)(vbase + off + 32 * 1024);
    }
    __builtin_amdgcn_sched_barrier(0);
    // hoisted B_all + mask-bit loads
    ushortx4 b4[4];
#pragma unroll
    for (int mf = 0; mf < 4; ++mf)
      b4[mf] = *(const ushortx4*)&B_all[ballrow + s0 + mf * 16 + lg * 4];
    uint2 mw = *(const uint2*)&mrow[s0 >> 5];
    unsigned long long wb = ((unsigned long long)mw.y << 32) | mw.x;
    __builtin_amdgcn_sched_barrier(0);
    // S^T tile: mfma(A=K[s,d], B=Q[t,d]) -> D[s][t]
    fx4 st[4];
#pragma unroll
    for (int mf = 0; mf < 4; ++mf) {
      fx4 c4 = {};
#pragma unroll
      for (int ks = 0; ks < 2; ++ks) {
        short8 kf = *(const short8*)&lK[mf * 16 + l15][ks * 32 + lg * 8];
        c4 = MFMA(kf, qf[ks], c4);
      }
      st[mf] = c4;
    }
    float p[16];
    float mt = -INFINITY;
#pragma unroll
    for (int mf = 0; mf < 4; ++mf) {
#pragma unroll
      for (int r = 0; r < 4; ++r) {
        float sv = (st[mf][r] + bf2f(b4[mf][r])) * 0.125f;
        int sl = mf * 16 + lg * 4 + r;
        if (!((wb >> sl) & 1ull)) sv = -INFINITY;
        p[mf * 4 + r] = sv;
        mt = fmaxf(mt, sv);
      }
    }
    mt = fmaxf(mt, __shfl_xor(mt, 16));
    mt = fmaxf(mt, __shfl_xor(mt, 32));
    float mnew = fmaxf(mrun, mt);
    float alpha = (mnew == -INFINITY) ? 1.f : __expf(mrun - mnew);
    mrun = mnew;
    float ps = 0.f;
#pragma unroll
    for (int i = 0; i < 16; ++i) {
      float pv = (mnew == -INFINITY) ? 0.f : __expf(p[i] - mnew);
      p[i] = pv;
      ps += pv;
    }
    ps += __shfl_xor(ps, 16);
    ps += __shfl_xor(ps, 32);
    lsum = lsum * alpha + ps;
#pragma unroll
    for (int mf = 0; mf < 4; ++mf) {
      ushortx4 pk4;
#pragma unroll
      for (int r = 0; r < 4; ++r) pk4[r] = f2bf(p[mf * 4 + r]);
      *(ushortx4*)&lP[wave][l15][mf * 16 + lg * 4] = pk4;
    }
    float aw[4];
#pragma unroll
    for (int r = 0; r < 4; ++r) aw[r] = __shfl(alpha, lg * 4 + r);
#pragma unroll
    for (int nf = 0; nf < 4; ++nf)
#pragma unroll
      for (int r = 0; r < 4; ++r) o[nf][r] *= aw[r];
    // PV: mfma(A=P[t,s], B=V[s,d]) -> D[t][d]
#pragma unroll
    for (int ks = 0; ks < 2; ++ks) {
      short8 pf = *(const short8*)&lP[wave][l15][ks * 32 + lg * 8];
#pragma unroll
      for (int nf = 0; nf < 4; ++nf) {
        int d_ = nf * 16 + l15;
        int sb_ = (ks * 32 + lg * 8 + 8 * (d_ >> 3)) & 63;
        short8 vf = *(const short8*)&lVt[d_][sb_];
        o[nf] = MFMA(pf, vf, o[nf]);
      }
    }
  }
  float rl = (lsum > 0.f) ? 1.f / lsum : 0.f;
  float rw[4];
#pragma unroll
  for (int r = 0; r < 4; ++r) rw[r] = __shfl(rl, lg * 4 + r);
#pragma unroll
  for (int nf = 0; nf < 4; ++nf)
#pragma unroll
    for (int r = 0; r < 4; ++r) {
      float val = o[nf][r] * rw[r];
      out[((size_t)(b * 1024 + tw + lg * 4 + r)) * 1024 + h * 64 + nf * 16 + l15] = f2bf(val);
    }
}

extern "C" void kernel_launch(void* const* d_in, const int* in_sizes, int n_in, void* d_out,
                              int out_size, void* d_ws, size_t ws_size, hipStream_t stream) {
  (void)in_sizes; (void)n_in; (void)out_size; (void)ws_size;
  const float* x = (const float*)d_in[0];
  const float* pos_k = (const float*)d_in[1];
  const int* mask = (const int*)d_in[2];
  const float* ln_scale = (const float*)d_in[3];
  const float* ln_bias = (const float*)d_in[4];
  const float* wq = (const float*)d_in[5];
  const float* bq = (const float*)d_in[6];
  const float* wk = (const float*)d_in[7];
  const float* bk = (const float*)d_in[8];
  const float* wv = (const float*)d_in[9];
  const float* bv = (const float*)d_in[10];
  const float* wo = (const float*)d_in[11];
  const float* bo = (const float*)d_in[12];
  float* out = (float*)d_out;
  char* ws = (char*)d_ws;
  const size_t MB = 1ull << 20;
  ushort_t* xn = (ushort_t*)(ws + 0 * MB);   // 16 MB; region reused for mbits after QKV
  ushort_t* qb = (ushort_t*)(ws + 16 * MB);
  ushort_t* kb = (ushort_t*)(ws + 32 * MB);
  ushort_t* vb = (ushort_t*)(ws + 48 * MB);
  ushort_t* ao = (ushort_t*)(ws + 64 * MB);
  ushort_t* wqb = (ushort_t*)(ws + 80 * MB);
  ushort_t* wkb = (ushort_t*)(ws + 82 * MB);
  ushort_t* wvb = (ushort_t*)(ws + 84 * MB);
  ushort_t* wob = (ushort_t*)(ws + 86 * MB);
  ushort_t* ball = (ushort_t*)(ws + 88 * MB);  // 256 MB -> ws >= 344 MB
  unsigned* mbits = (unsigned*)(ws + 0 * MB);  // 1 MB, reuses xn region (dead after QKV)

  cvt4_kernel<<<4096, 256, 0, stream>>>(wq, wk, wv, wo, wqb, wkb, wvb, wob);
  ln_kernel<<<8192, 256, 0, stream>>>(x, ln_scale, ln_bias, xn);
  dim3 gg(8, 64);
  gemm_bt<0><<<gg, 256, 0, stream>>>(xn, wqb, bq, qb, 8192, 1024, 1024);
  gemm_bt<0><<<gg, 256, 0, stream>>>(xn, wkb, bk, kb, 8192, 1024, 1024);
  gemm_bt<0><<<gg, 256, 0, stream>>>(xn, wvb, bv, vb, 8192, 1024, 1024);
  maskpack_kernel<<<8192, 256, 0, stream>>>(mask, mbits);  // after QKV: xn region now free
  ball_kernel<<<dim3(2, 1024), 256, 0, stream>>>(qb, pos_k, ball);
  attn_kernel<<<dim3(16, 128), 256, 0, stream>>>(qb, kb, vb, ball, mbits, ao);
  gemm_bt<1><<<gg, 256, 0, stream>>>(ao, wob, bo, out, 8192, 1024, 1024);
}